// Round 6
// baseline (172.574 us; speedup 1.0000x reference)
//
#include <hip/hip_runtime.h>
#include <hip/hip_bf16.h>

#define B_    16
#define N_    4
#define COUT  256
#define CIN   256
#define H_    64
#define W_    64
#define K_TOT (CIN * 9)   // 2304, k = p*256 + cin  (p-major)
#define HW    (H_ * W_)   // 4096
#define NT    (K_TOT / 32) // 72 k-tiles

typedef __attribute__((ext_vector_type(8))) short short8;
typedef __attribute__((ext_vector_type(4))) float f32x4;
typedef unsigned short ushort_t;

static __device__ __forceinline__ ushort_t f2bf(float f) {
    __hip_bfloat16 h = __float2bfloat16(f);
    return *reinterpret_cast<ushort_t*>(&h);
}

// ---------------------------------------------------------------------------
// Kernel 1: 9x9 rotation matrices, scaled by alpha.  rm[b*N_+n][9][9] floats.
// ---------------------------------------------------------------------------
__global__ void rot_mats_kernel(const float* __restrict__ alphas,
                                const float* __restrict__ angles,
                                float* __restrict__ rm) {
    int i = threadIdx.x;
    if (i >= B_ * N_) return;
    float th = angles[i], al = alphas[i];
    float xc = cosf(th), ys = sinf(th);
    float a = xc - ys, b = xc * ys, c = xc + ys;
    float r[81];
#pragma unroll
    for (int j = 0; j < 81; ++j) r[j] = 0.f;
    if (th >= 0.f) {
        r[0] = a;          r[1] = 1.f - a;
        r[10] = xc - b;    r[11] = b;        r[13] = 1.f - c + b; r[14] = ys - b;
        r[20] = a;         r[23] = 1.f - a;
        r[27] = b;         r[28] = ys - b;   r[30] = xc - b;      r[31] = 1.f - c + b;
        r[40] = 1.f;
        r[49] = 1.f - c + b; r[50] = xc - b; r[52] = ys - b;      r[53] = b;
        r[57] = 1.f - a;   r[60] = a;
        r[66] = ys - b;    r[67] = 1.f - c + b; r[69] = b;        r[70] = xc - b;
        r[79] = 1.f - a;   r[80] = a;
    } else {
        r[0] = c;          r[3] = 1.f - c;
        r[9] = -b;         r[10] = xc + b;   r[12] = b - ys;      r[13] = 1.f - a - b;
        r[19] = 1.f - c;   r[20] = c;
        r[30] = xc + b;    r[31] = 1.f - a - b; r[33] = -b;       r[34] = b - ys;
        r[40] = 1.f;
        r[46] = b - ys;    r[47] = -b;       r[49] = 1.f - a - b; r[50] = xc + b;
        r[60] = c;         r[61] = 1.f - c;
        r[67] = 1.f - a - b; r[68] = b - ys; r[70] = xc + b;      r[71] = -b;
        r[77] = 1.f - c;   r[80] = c;
    }
#pragma unroll
    for (int j = 0; j < 81; ++j) rm[i * 81 + j] = r[j] * al;
}

// ---------------------------------------------------------------------------
// Kernel 2: rw[b][cout][p*256 + cin] (bf16, p-major K layout)
// ---------------------------------------------------------------------------
__global__ __launch_bounds__(256)
void build_rw_kernel(const float* __restrict__ weight,
                     const float* __restrict__ rm,
                     ushort_t* __restrict__ rw) {
    __shared__ float rms[N_ * 81];        // 324 floats
    int tid = threadIdx.x;
    int b = blockIdx.y;
    for (int j = tid; j < N_ * 81; j += 256)
        rms[j] = rm[b * N_ * 81 + j];
    __syncthreads();

    int idx = blockIdx.x * 256 + tid;     // cout*256 + cin
    int cout = idx >> 8, cin = idx & 255;

    float wv[N_][9];
#pragma unroll
    for (int n = 0; n < N_; ++n)
#pragma unroll
        for (int q = 0; q < 9; ++q)
            wv[n][q] = weight[(size_t)(n * (COUT * CIN) + idx) * 9 + q];

    ushort_t* dst = rw + (size_t)(b * COUT + cout) * K_TOT + cin;
#pragma unroll
    for (int p = 0; p < 9; ++p) {
        float s = 0.f;
#pragma unroll
        for (int n = 0; n < N_; ++n)
#pragma unroll
            for (int q = 0; q < 9; ++q)
                s += rms[n * 81 + p * 9 + q] * wv[n][q];
        dst[p * 256] = f2bf(s);
    }
}

// ---------------------------------------------------------------------------
// Kernel 2b: NHWC repack: x fp32 [b][c][pix] -> xt bf16 [b][pix][c]
// Tile 64c x 64px via LDS. grid (HW/64, CIN/64, B_).
// ---------------------------------------------------------------------------
__global__ __launch_bounds__(256)
void nhwc_kernel(const float* __restrict__ x, ushort_t* __restrict__ xt) {
    int p0 = blockIdx.x * 64;
    int c0 = blockIdx.y * 64;
    int b  = blockIdx.z;
    __shared__ ushort_t tileT[64][72];    // [px][c], row 144B (16B-aligned)
    int t = threadIdx.x;

    // stage 1: read 64c x 64px fp32 (coalesced along px), write transposed
    int ci = t & 63, jseg = t >> 6;       // 4 segs x 16 px
    const float* src = x + ((size_t)(b * CIN + c0 + ci) * HW + p0 + jseg * 16);
    float4 f[4];
#pragma unroll
    for (int q = 0; q < 4; ++q) f[q] = ((const float4*)src)[q];
#pragma unroll
    for (int q = 0; q < 16; ++q)
        tileT[jseg * 16 + q][ci] = f2bf(((const float*)f)[q]);
    __syncthreads();

    // stage 2: write rows of 64 c (coalesced along c)
    int j = t >> 2, cseg = t & 3;         // 64 px x 4 segs of 16 c
    ushort_t* dst = xt + ((size_t)b * HW + p0 + j) * CIN + c0 + cseg * 16;
    int4 v0 = *(const int4*)(&tileT[j][cseg * 16]);
    int4 v1 = *(const int4*)(&tileT[j][cseg * 16 + 8]);
    *(int4*)dst = v0;
    *(int4*)(dst + 8) = v1;
}

// ---------------------------------------------------------------------------
// Kernel 3: implicit-GEMM conv. 128 cout x 128 px tile, dbuf LDS,
// single barrier per k-tile, reg-staged prefetch (T14), NHWC B-gather
// (2x b128 per thread), LDS slot swizzle, bijective XCD swizzle (T1).
// ---------------------------------------------------------------------------
__global__ __launch_bounds__(256)
void conv_kernel(const ushort_t* __restrict__ xt,
                 const ushort_t* __restrict__ rw,
                 float* __restrict__ out) {
    int bid0 = blockIdx.x;
    int bid = (bid0 & 7) * 128 + (bid0 >> 3);   // grid=1024: bijective
    int mt = bid & 1;            // cout tile (2)
    int rp = (bid >> 1) & 31;    // row pair
    int b  = bid >> 6;           // sample
    int m0 = mt * 128;
    int y0 = rp * 2;
    int tid = threadIdx.x;

    __shared__ __align__(16) ushort_t As[2][128][32];   // 2 x 8 KB
    __shared__ __align__(16) ushort_t Bs[2][128][32];   // 2 x 8 KB

    int lane = tid & 63;
    int wid  = tid >> 6;
    int wr = wid >> 1, wc = wid & 1;

    f32x4 acc[4][4] = {};

    const ushort_t* rwb = rw + (size_t)(b * COUT + m0) * K_TOT;
    const ushort_t* xtb = xt + (size_t)b * HW * CIN;

    // A staging: thread -> row tid>>1, segs {0,1} or {2,3}
    int ar0 = tid >> 1, aseg0 = (tid & 1) * 2;
    // B staging: thread -> px tid&127, cin-half tid>>7 (16 cin each)
    int bpx  = tid & 127;
    int bsub = tid >> 7;
    int prow = bpx >> 6;
    int xcol = bpx & 63;

    int4 pa0, pa1; short8 pv0, pv1;

#define SWZ(seg, row) ((((seg) + ((row) >> 1)) & 3) * 8)

#define LOAD_TILE(KT)                                                          \
    {                                                                          \
        int k0 = (KT) * 32;                                                    \
        pa0 = *(const int4*)(rwb + (size_t)ar0 * K_TOT + k0 + aseg0 * 8);      \
        pa1 = *(const int4*)(rwb + (size_t)ar0 * K_TOT + k0 + aseg0 * 8 + 8);  \
        int p = k0 >> 8; int cin0 = k0 & 255;                                  \
        int ph = p / 3, pw = p - 3 * ph;                                       \
        int yy = y0 + prow + ph - 1, xx = xcol + pw - 1;                       \
        bool ok = ((unsigned)yy < (unsigned)H_) && ((unsigned)xx < (unsigned)W_); \
        const ushort_t* gp = xtb + ((size_t)((yy & 63) * 64 + (xx & 63))) * CIN \
                             + cin0 + bsub * 16;                               \
        short8 t0 = *(const short8*)gp;                                        \
        short8 t1 = *(const short8*)(gp + 8);                                  \
        pv0 = ok ? t0 : short8{};                                              \
        pv1 = ok ? t1 : short8{};                                              \
    }

#define WRITE_TILE(BUF)                                                        \
    {                                                                          \
        *(int4*)(&As[BUF][ar0][SWZ(aseg0, ar0)]) = pa0;                        \
        *(int4*)(&As[BUF][ar0][SWZ(aseg0 + 1, ar0)]) = pa1;                    \
        *(short8*)(&Bs[BUF][bpx][SWZ(2 * bsub, bpx)]) = pv0;                   \
        *(short8*)(&Bs[BUF][bpx][SWZ(2 * bsub + 1, bpx)]) = pv1;               \
    }

    LOAD_TILE(0);
    WRITE_TILE(0);
    __syncthreads();

    int kseg = lane >> 4;      // fragment k-seg 0..3
    int rA   = lane & 15;
    int cur = 0;

    for (int kt = 0; kt < NT; ++kt) {
        if (kt + 1 < NT) LOAD_TILE(kt + 1);

        short8 af[4], bf[4];
#pragma unroll
        for (int mi = 0; mi < 4; ++mi) {
            int row = wr * 64 + mi * 16 + rA;
            af[mi] = *(const short8*)(&As[cur][row][SWZ(kseg, row)]);
        }
#pragma unroll
        for (int ni = 0; ni < 4; ++ni) {
            int row = wc * 64 + ni * 16 + rA;
            bf[ni] = *(const short8*)(&Bs[cur][row][SWZ(kseg, row)]);
        }
#pragma unroll
        for (int mi = 0; mi < 4; ++mi)
#pragma unroll
            for (int ni = 0; ni < 4; ++ni)
                acc[mi][ni] = __builtin_amdgcn_mfma_f32_16x16x32_bf16(af[mi], bf[ni], acc[mi][ni], 0, 0, 0);

        if (kt + 1 < NT) {
            WRITE_TILE(cur ^ 1);
            __syncthreads();
        }
        cur ^= 1;
    }
#undef LOAD_TILE
#undef WRITE_TILE
#undef SWZ

    // ---- epilogue: D[row=(lane>>4)*4+r][col=lane&15] ----
    int row0 = (lane >> 4) * 4;
    int col  = lane & 15;
    float* outb = out + (size_t)(b * COUT + m0) * HW + (size_t)y0 * W_;
#pragma unroll
    for (int mi = 0; mi < 4; ++mi)
#pragma unroll
        for (int ni = 0; ni < 4; ++ni)
#pragma unroll
            for (int r = 0; r < 4; ++r) {
                int m = wr * 64 + mi * 16 + row0 + r;
                int n = wc * 64 + ni * 16 + col;
                outb[(size_t)m * HW + n] = acc[mi][ni][r];
            }
}

// ---------------------------------------------------------------------------
extern "C" void kernel_launch(void* const* d_in, const int* in_sizes, int n_in,
                              void* d_out, int out_size, void* d_ws, size_t ws_size,
                              hipStream_t stream) {
    const float* x      = (const float*)d_in[0];
    const float* alphas = (const float*)d_in[1];
    const float* angles = (const float*)d_in[2];
    const float* weight = (const float*)d_in[3];
    float* out = (float*)d_out;

    ushort_t* rw = (ushort_t*)d_ws;                                          // 18.9 MB
    ushort_t* xt = (ushort_t*)((char*)d_ws + (size_t)B_ * COUT * K_TOT * 2); // 33.6 MB
    float*    rm = (float*)((char*)d_ws + (size_t)B_ * COUT * K_TOT * 2
                                        + (size_t)B_ * CIN * HW * 2);        // 20.7 KB

    rot_mats_kernel<<<1, 64, 0, stream>>>(alphas, angles, rm);
    build_rw_kernel<<<dim3(COUT * CIN / 256, B_), 256, 0, stream>>>(weight, rm, rw);
    nhwc_kernel<<<dim3(HW / 64, CIN / 64, B_), 256, 0, stream>>>(x, xt);
    conv_kernel<<<B_ * 32 * 2, 256, 0, stream>>>(xt, rw, out);
}

// Round 7
// 139.744 us; speedup vs baseline: 1.2349x; 1.2349x over previous
//
#include <hip/hip_runtime.h>
#include <hip/hip_bf16.h>

#define B_    16
#define N_    4
#define COUT  256
#define CIN   256
#define H_    64
#define W_    64
#define K_TOT (CIN * 9)   // 2304, k = p*256 + cin (p-major)
#define HW    (H_ * W_)   // 4096
#define NT    (K_TOT / 32) // 72 k-tiles
#define PAD   66
#define PLANE (PAD * PAD) // 4356 padded pixels per (b, cin-block) plane

typedef __attribute__((ext_vector_type(8))) short short8;
typedef __attribute__((ext_vector_type(4))) float f32x4;
typedef unsigned short ushort_t;

static __device__ __forceinline__ ushort_t f2bf(float f) {
    __hip_bfloat16 h = __float2bfloat16(f);
    return *reinterpret_cast<ushort_t*>(&h);
}

typedef __attribute__((address_space(3))) unsigned int lds_u32;
typedef __attribute__((address_space(1))) const unsigned int glb_u32;
static __device__ __forceinline__ void gl_lds16(const ushort_t* g, ushort_t* l) {
    __builtin_amdgcn_global_load_lds((glb_u32*)g, (lds_u32*)l, 16, 0, 0);
}

// ---------------------------------------------------------------------------
// Kernel 1: 9x9 rotation matrices, scaled by alpha.  rm[b*N_+n][9][9] floats.
// ---------------------------------------------------------------------------
__global__ void rot_mats_kernel(const float* __restrict__ alphas,
                                const float* __restrict__ angles,
                                float* __restrict__ rm) {
    int i = threadIdx.x;
    if (i >= B_ * N_) return;
    float th = angles[i], al = alphas[i];
    float xc = cosf(th), ys = sinf(th);
    float a = xc - ys, b = xc * ys, c = xc + ys;
    float r[81];
#pragma unroll
    for (int j = 0; j < 81; ++j) r[j] = 0.f;
    if (th >= 0.f) {
        r[0] = a;          r[1] = 1.f - a;
        r[10] = xc - b;    r[11] = b;        r[13] = 1.f - c + b; r[14] = ys - b;
        r[20] = a;         r[23] = 1.f - a;
        r[27] = b;         r[28] = ys - b;   r[30] = xc - b;      r[31] = 1.f - c + b;
        r[40] = 1.f;
        r[49] = 1.f - c + b; r[50] = xc - b; r[52] = ys - b;      r[53] = b;
        r[57] = 1.f - a;   r[60] = a;
        r[66] = ys - b;    r[67] = 1.f - c + b; r[69] = b;        r[70] = xc - b;
        r[79] = 1.f - a;   r[80] = a;
    } else {
        r[0] = c;          r[3] = 1.f - c;
        r[9] = -b;         r[10] = xc + b;   r[12] = b - ys;      r[13] = 1.f - a - b;
        r[19] = 1.f - c;   r[20] = c;
        r[30] = xc + b;    r[31] = 1.f - a - b; r[33] = -b;       r[34] = b - ys;
        r[40] = 1.f;
        r[46] = b - ys;    r[47] = -b;       r[49] = 1.f - a - b; r[50] = xc + b;
        r[60] = c;         r[61] = 1.f - c;
        r[67] = 1.f - a - b; r[68] = b - ys; r[70] = xc + b;      r[71] = -b;
        r[77] = 1.f - c;   r[80] = c;
    }
#pragma unroll
    for (int j = 0; j < 81; ++j) rm[i * 81 + j] = r[j] * al;
}

// ---------------------------------------------------------------------------
// Kernel 2: rw[b][cout][p*256 + cin] (bf16, p-major K layout)
// ---------------------------------------------------------------------------
__global__ __launch_bounds__(256)
void build_rw_kernel(const float* __restrict__ weight,
                     const float* __restrict__ rm,
                     ushort_t* __restrict__ rw) {
    __shared__ float rms[N_ * 81];        // 324 floats
    int tid = threadIdx.x;
    int b = blockIdx.y;
    for (int j = tid; j < N_ * 81; j += 256)
        rms[j] = rm[b * N_ * 81 + j];
    __syncthreads();

    int idx = blockIdx.x * 256 + tid;     // cout*256 + cin
    int cout = idx >> 8, cin = idx & 255;

    float wv[N_][9];
#pragma unroll
    for (int n = 0; n < N_; ++n)
#pragma unroll
        for (int q = 0; q < 9; ++q)
            wv[n][q] = weight[(size_t)(n * (COUT * CIN) + idx) * 9 + q];

    ushort_t* dst = rw + (size_t)(b * COUT + cout) * K_TOT + cin;
#pragma unroll
    for (int p = 0; p < 9; ++p) {
        float s = 0.f;
#pragma unroll
        for (int n = 0; n < N_; ++n)
#pragma unroll
            for (int q = 0; q < 9; ++q)
                s += rms[n * 81 + p * 9 + q] * wv[n][q];
        dst[p * 256] = f2bf(s);
    }
}

// ---------------------------------------------------------------------------
// Kernel 2a: zero the halo ring of each padded plane (260 px x 32 cin).
// grid: 128 planes (b*8+cb).
// ---------------------------------------------------------------------------
__global__ __launch_bounds__(256)
void halo_zero_kernel(ushort_t* __restrict__ xt) {
    ushort_t* base = xt + (size_t)blockIdx.x * PLANE * 32;
    int t = threadIdx.x;
    for (int i = t; i < 260; i += 256) {
        int py, px;
        if (i < 66)       { py = 0;  px = i; }
        else if (i < 132) { py = 65; px = i - 66; }
        else if (i < 196) { py = i - 132 + 1; px = 0; }
        else              { py = i - 196 + 1; px = 65; }
        ushort_t* d = base + (size_t)(py * PAD + px) * 32;
        int4 z = {0, 0, 0, 0};
        *(int4*)d = z; *(int4*)(d + 8) = z;
        *(int4*)(d + 16) = z; *(int4*)(d + 24) = z;
    }
}

// ---------------------------------------------------------------------------
// Kernel 2b: interior repack: x fp32 [b][c][64][64] -> xt bf16
//   [b][cb(8)][y+1][x+1][32cin].  grid (64 rows, 8 cb, B_), 256 thr.
// ---------------------------------------------------------------------------
__global__ __launch_bounds__(256)
void nhwc_kernel(const float* __restrict__ x, ushort_t* __restrict__ xt) {
    int y  = blockIdx.x;
    int cb = blockIdx.y;
    int b  = blockIdx.z;
    __shared__ ushort_t tileT[64][40];    // [px][ci], 80B rows (16B multiple)
    int t = threadIdx.x;

    int ci = t & 31, seg = t >> 5;        // 8 segs x 8 px
    const float* src = x + ((size_t)(b * CIN + cb * 32 + ci) * HW + y * 64 + seg * 8);
    float4 f0 = ((const float4*)src)[0];
    float4 f1 = ((const float4*)src)[1];
#pragma unroll
    for (int q = 0; q < 4; ++q) tileT[seg * 8 + q][ci]     = f2bf(((float*)&f0)[q]);
#pragma unroll
    for (int q = 0; q < 4; ++q) tileT[seg * 8 + 4 + q][ci] = f2bf(((float*)&f1)[q]);
    __syncthreads();

    int px = t >> 2, cseg = t & 3;        // 64 px x 4 x 16B
    ushort_t* dst = xt + ((size_t)(b * 8 + cb) * PLANE + (y + 1) * PAD + px + 1) * 32
                       + cseg * 8;
    *(int4*)dst = *(const int4*)&tileT[px][cseg * 8];
}

// ---------------------------------------------------------------------------
// Kernel 3: implicit-GEMM conv. 128 cout x 128 px tile, dbuf LDS, 1 barrier
// per k-tile, staging via global_load_lds dwordx4 (linear LDS dest +
// inverse-swizzled global source, XOR s^(r&3) both sides), XCD swizzle.
// ---------------------------------------------------------------------------
__global__ __launch_bounds__(256)
void conv_kernel(const ushort_t* __restrict__ xt,
                 const ushort_t* __restrict__ rw,
                 float* __restrict__ out) {
    int bid0 = blockIdx.x;
    int bid = (bid0 & 7) * 128 + (bid0 >> 3);   // grid=1024: bijective
    int mt = bid & 1;            // cout tile (2)
    int rp = (bid >> 1) & 31;    // row pair
    int b  = bid >> 6;           // sample
    int m0 = mt * 128;
    int y0 = rp * 2;
    int tid = threadIdx.x;
    int lane = tid & 63;
    int wid  = tid >> 6;
    int wr = wid >> 1, wc = wid & 1;

    __shared__ __align__(16) ushort_t As[2][128][32];   // 2 x 8 KB
    __shared__ __align__(16) ushort_t Bs[2][128][32];   // 2 x 8 KB

    f32x4 acc[4][4] = {};

    const ushort_t* rwb = rw + (size_t)(b * COUT + m0) * K_TOT;
    const ushort_t* xb  = xt + (size_t)b * 8 * PLANE * 32;

    // staging unit u = wid*128 + i*64 + lane; r = u>>2 (row), s = u&3 (16B seg)
    int u0 = wid * 128 + lane;
    int u1 = u0 + 64;
    int r0 = u0 >> 2, s0 = u0 & 3;
    int r1 = u1 >> 2, s1 = u1 & 3;
    // A source: inverse-swizzled seg
    size_t aoff0 = (size_t)r0 * K_TOT + (size_t)((s0 ^ (r0 & 3)) * 8);
    size_t aoff1 = (size_t)r1 * K_TOT + (size_t)((s1 ^ (r1 & 3)) * 8);
    // B source: pixel row r -> (prow, xcol), swizzled seg
    int prow0 = r0 >> 6, xcol0 = r0 & 63, bs0 = (s0 ^ (r0 & 3)) * 8;
    int prow1 = r1 >> 6, xcol1 = r1 & 63, bs1 = (s1 ^ (r1 & 3)) * 8;

    ushort_t* A0 = &As[0][0][0];
    ushort_t* B0 = &Bs[0][0][0];

#define STAGE(BUF, KT)                                                         \
    {                                                                          \
        int k0 = (KT) * 32;                                                    \
        int p = (KT) >> 3, cb = (KT) & 7;                                      \
        int ph = p / 3, pw = p - 3 * ph;                                       \
        gl_lds16(rwb + aoff0 + k0, A0 + (size_t)(BUF) * 4096 + u0 * 8);        \
        gl_lds16(rwb + aoff1 + k0, A0 + (size_t)(BUF) * 4096 + u1 * 8);        \
        const ushort_t* xc = xb + (size_t)cb * PLANE * 32;                     \
        gl_lds16(xc + (size_t)((y0 + prow0 + ph) * PAD + xcol0 + pw) * 32 + bs0,\
                 B0 + (size_t)(BUF) * 4096 + u0 * 8);                          \
        gl_lds16(xc + (size_t)((y0 + prow1 + ph) * PAD + xcol1 + pw) * 32 + bs1,\
                 B0 + (size_t)(BUF) * 4096 + u1 * 8);                          \
    }

    STAGE(0, 0);
    __syncthreads();

    int kseg = lane >> 4;      // fragment k-seg 0..3
    int rA   = lane & 15;
    int cur = 0;

    for (int kt = 0; kt < NT; ++kt) {
        if (kt + 1 < NT) STAGE(cur ^ 1, kt + 1);

        short8 af[4], bf[4];
#pragma unroll
        for (int mi = 0; mi < 4; ++mi) {
            int row = wr * 64 + mi * 16 + rA;
            af[mi] = *(const short8*)(&As[cur][row][(kseg ^ (row & 3)) * 8]);
        }
#pragma unroll
        for (int ni = 0; ni < 4; ++ni) {
            int row = wc * 64 + ni * 16 + rA;
            bf[ni] = *(const short8*)(&Bs[cur][row][(kseg ^ (row & 3)) * 8]);
        }
#pragma unroll
        for (int mi = 0; mi < 4; ++mi)
#pragma unroll
            for (int ni = 0; ni < 4; ++ni)
                acc[mi][ni] = __builtin_amdgcn_mfma_f32_16x16x32_bf16(af[mi], bf[ni], acc[mi][ni], 0, 0, 0);

        __syncthreads();
        cur ^= 1;
    }
#undef STAGE

    // ---- epilogue: D[row=(lane>>4)*4+r][col=lane&15] ----
    int row0 = (lane >> 4) * 4;
    int col  = lane & 15;
    float* outb = out + (size_t)(b * COUT + m0) * HW + (size_t)y0 * W_;
#pragma unroll
    for (int mi = 0; mi < 4; ++mi)
#pragma unroll
        for (int ni = 0; ni < 4; ++ni)
#pragma unroll
            for (int r = 0; r < 4; ++r) {
                int m = wr * 64 + mi * 16 + row0 + r;
                int n = wc * 64 + ni * 16 + col;
                outb[(size_t)m * HW + n] = acc[mi][ni][r];
            }
}

// ---------------------------------------------------------------------------
extern "C" void kernel_launch(void* const* d_in, const int* in_sizes, int n_in,
                              void* d_out, int out_size, void* d_ws, size_t ws_size,
                              hipStream_t stream) {
    const float* x      = (const float*)d_in[0];
    const float* alphas = (const float*)d_in[1];
    const float* angles = (const float*)d_in[2];
    const float* weight = (const float*)d_in[3];
    float* out = (float*)d_out;

    // ws: rw 18.87 MB | xt 35.68 MB | rm 20.7 KB  (~54.6 MB total)
    ushort_t* rw = (ushort_t*)d_ws;
    ushort_t* xt = (ushort_t*)((char*)d_ws + (size_t)B_ * COUT * K_TOT * 2);
    float*    rm = (float*)((char*)d_ws + (size_t)B_ * COUT * K_TOT * 2
                                        + (size_t)128 * PLANE * 32 * 2);

    rot_mats_kernel<<<1, 64, 0, stream>>>(alphas, angles, rm);
    build_rw_kernel<<<dim3(COUT * CIN / 256, B_), 256, 0, stream>>>(weight, rm, rw);
    halo_zero_kernel<<<128, 256, 0, stream>>>(xt);
    nhwc_kernel<<<dim3(64, 8, B_), 256, 0, stream>>>(x, xt);
    conv_kernel<<<B_ * 32 * 2, 256, 0, stream>>>(xt, rw, out);
}

// Round 8
// 117.120 us; speedup vs baseline: 1.4735x; 1.1932x over previous
//
#include <hip/hip_runtime.h>
#include <hip/hip_bf16.h>

#define B_    16
#define N_    4
#define COUT  256
#define CIN   256
#define H_    64
#define W_    64
#define K_TOT (CIN * 9)    // 2304, k = p*256 + cin (p-major)
#define HW    (H_ * W_)    // 4096
#define NKT   (K_TOT / 64) // 36 K-tiles of 64
#define PAD   66
#define PLANE (PAD * PAD)  // 4356 padded pixels per (b, cb4) plane

typedef __attribute__((ext_vector_type(8))) short short8;
typedef __attribute__((ext_vector_type(4))) float f32x4;
typedef unsigned short ushort_t;

static __device__ __forceinline__ ushort_t f2bf(float f) {
    __hip_bfloat16 h = __float2bfloat16(f);
    return *reinterpret_cast<ushort_t*>(&h);
}

typedef __attribute__((address_space(3))) unsigned int lds_u32;
typedef __attribute__((address_space(1))) const unsigned int glb_u32;
static __device__ __forceinline__ void gl_lds16(const ushort_t* g, ushort_t* l) {
    __builtin_amdgcn_global_load_lds((glb_u32*)g, (lds_u32*)l, 16, 0, 0);
}

#define BARRIER() asm volatile("s_barrier" ::: "memory")
#define VMCNT0()  asm volatile("s_waitcnt vmcnt(0)" ::: "memory")

// ---------------------------------------------------------------------------
// Kernel 1: 9x9 rotation matrices, scaled by alpha.  rm[b*N_+n][9][9] floats.
// ---------------------------------------------------------------------------
__global__ void rot_mats_kernel(const float* __restrict__ alphas,
                                const float* __restrict__ angles,
                                float* __restrict__ rm) {
    int i = threadIdx.x;
    if (i >= B_ * N_) return;
    float th = angles[i], al = alphas[i];
    float xc = cosf(th), ys = sinf(th);
    float a = xc - ys, b = xc * ys, c = xc + ys;
    float r[81];
#pragma unroll
    for (int j = 0; j < 81; ++j) r[j] = 0.f;
    if (th >= 0.f) {
        r[0] = a;          r[1] = 1.f - a;
        r[10] = xc - b;    r[11] = b;        r[13] = 1.f - c + b; r[14] = ys - b;
        r[20] = a;         r[23] = 1.f - a;
        r[27] = b;         r[28] = ys - b;   r[30] = xc - b;      r[31] = 1.f - c + b;
        r[40] = 1.f;
        r[49] = 1.f - c + b; r[50] = xc - b; r[52] = ys - b;      r[53] = b;
        r[57] = 1.f - a;   r[60] = a;
        r[66] = ys - b;    r[67] = 1.f - c + b; r[69] = b;        r[70] = xc - b;
        r[79] = 1.f - a;   r[80] = a;
    } else {
        r[0] = c;          r[3] = 1.f - c;
        r[9] = -b;         r[10] = xc + b;   r[12] = b - ys;      r[13] = 1.f - a - b;
        r[19] = 1.f - c;   r[20] = c;
        r[30] = xc + b;    r[31] = 1.f - a - b; r[33] = -b;       r[34] = b - ys;
        r[40] = 1.f;
        r[46] = b - ys;    r[47] = -b;       r[49] = 1.f - a - b; r[50] = xc + b;
        r[60] = c;         r[61] = 1.f - c;
        r[67] = 1.f - a - b; r[68] = b - ys; r[70] = xc + b;      r[71] = -b;
        r[77] = 1.f - c;   r[80] = c;
    }
#pragma unroll
    for (int j = 0; j < 81; ++j) rm[i * 81 + j] = r[j] * al;
}

// ---------------------------------------------------------------------------
// Kernel 2: rw[b][cout][p*256 + cin] (bf16, p-major K layout)
// ---------------------------------------------------------------------------
__global__ __launch_bounds__(256)
void build_rw_kernel(const float* __restrict__ weight,
                     const float* __restrict__ rm,
                     ushort_t* __restrict__ rw) {
    __shared__ float rms[N_ * 81];        // 324 floats
    int tid = threadIdx.x;
    int b = blockIdx.y;
    for (int j = tid; j < N_ * 81; j += 256)
        rms[j] = rm[b * N_ * 81 + j];
    __syncthreads();

    int idx = blockIdx.x * 256 + tid;     // cout*256 + cin
    int cout = idx >> 8, cin = idx & 255;

    float wv[N_][9];
#pragma unroll
    for (int n = 0; n < N_; ++n)
#pragma unroll
        for (int q = 0; q < 9; ++q)
            wv[n][q] = weight[(size_t)(n * (COUT * CIN) + idx) * 9 + q];

    ushort_t* dst = rw + (size_t)(b * COUT + cout) * K_TOT + cin;
#pragma unroll
    for (int p = 0; p < 9; ++p) {
        float s = 0.f;
#pragma unroll
        for (int n = 0; n < N_; ++n)
#pragma unroll
            for (int q = 0; q < 9; ++q)
                s += rms[n * 81 + p * 9 + q] * wv[n][q];
        dst[p * 256] = f2bf(s);
    }
}

// ---------------------------------------------------------------------------
// Kernel 2a: zero the halo ring of each padded plane (260 px x 64 cin).
// grid: 64 planes (b*4 + cb4).
// ---------------------------------------------------------------------------
__global__ __launch_bounds__(256)
void halo_zero_kernel(ushort_t* __restrict__ xt) {
    ushort_t* base = xt + (size_t)blockIdx.x * PLANE * 64;
    int t = threadIdx.x;
    for (int i = t; i < 260; i += 256) {
        int py, px;
        if (i < 66)       { py = 0;  px = i; }
        else if (i < 132) { py = 65; px = i - 66; }
        else if (i < 196) { py = i - 132 + 1; px = 0; }
        else              { py = i - 196 + 1; px = 65; }
        ushort_t* d = base + (size_t)(py * PAD + px) * 64;
        int4 z = {0, 0, 0, 0};
#pragma unroll
        for (int q = 0; q < 8; ++q) *(int4*)(d + q * 8) = z;
    }
}

// ---------------------------------------------------------------------------
// Kernel 2b: interior repack: x fp32 [b][c][64][64] -> xt bf16
//   [b][cb4(4)][y+1][x+1][64cin].  grid (64 rows, 8 cb32, B_), 256 thr.
// ---------------------------------------------------------------------------
__global__ __launch_bounds__(256)
void nhwc_kernel(const float* __restrict__ x, ushort_t* __restrict__ xt) {
    int y    = blockIdx.x;
    int cb32 = blockIdx.y;
    int b    = blockIdx.z;
    __shared__ ushort_t tileT[64][40];    // [px][ci(32)], 80B rows
    int t = threadIdx.x;

    int ci = t & 31, seg = t >> 5;        // 8 segs x 8 px
    const float* src = x + ((size_t)(b * CIN + cb32 * 32 + ci) * HW + y * 64 + seg * 8);
    float4 f0 = ((const float4*)src)[0];
    float4 f1 = ((const float4*)src)[1];
#pragma unroll
    for (int q = 0; q < 4; ++q) tileT[seg * 8 + q][ci]     = f2bf(((float*)&f0)[q]);
#pragma unroll
    for (int q = 0; q < 4; ++q) tileT[seg * 8 + 4 + q][ci] = f2bf(((float*)&f1)[q]);
    __syncthreads();

    int px = t >> 2, cseg = t & 3;        // 64 px x 4 x 16B
    ushort_t* dst = xt + ((size_t)(b * 4 + (cb32 >> 1)) * PLANE + (y + 1) * PAD + px + 1) * 64
                       + (cb32 & 1) * 32 + cseg * 8;
    *(int4*)dst = *(const int4*)&tileT[px][cseg * 8];
}

// ---------------------------------------------------------------------------
// Kernel 3: 256x256 8-phase implicit-GEMM conv (HK-style T2+T3+T4+T5).
// 512 thr = 8 waves (2M x 4N), each wave 128x64, acc[8][4].
// BK=64 (one tap p, 64 cin). LDS 128 KiB dbuf. 4 phases/K-tile, 16 MFMA each.
// Stages: phase1 = A-halves of kt+1, phase2 = B-halves; vmcnt(0) @ phase 4.
// Swizzle involution seg^(row&7) on gload source and ds_read (both sides).
// ---------------------------------------------------------------------------
__global__ __launch_bounds__(512, 1)
void conv_kernel(const ushort_t* __restrict__ xt,
                 const ushort_t* __restrict__ rw,
                 float* __restrict__ out) {
    int bid0 = blockIdx.x;
    int bid = (bid0 & 7) * 32 + (bid0 >> 3);   // 256 = 8*32: bijective
    int b    = bid >> 4;
    int tile = bid & 15;        // pixel tile: 4 image rows
    int y0 = tile * 4;
    int tid = threadIdx.x;
    int lane = tid & 63, wid = tid >> 6;
    int wm = wid >> 2, wn = wid & 3;
    int rA = lane & 15, kseg = lane >> 4;

    __shared__ __align__(16) ushort_t As[2][256][64];   // 64 KB
    __shared__ __align__(16) ushort_t Bs[2][256][64];   // 64 KB
    ushort_t* AsB = &As[0][0][0];
    ushort_t* BsB = &Bs[0][0][0];

    f32x4 acc[8][4] = {};

    const ushort_t* rwb = rw + (size_t)b * COUT * K_TOT;
    const ushort_t* xtb = xt + (size_t)b * 4 * PLANE * 64;

    // ---- staging geometry: unit u = chunk*64+lane, r=u>>3, s=u&7 ----
    const int sd = (lane & 7) ^ (lane >> 3);    // source seg (involution)
    const int r0 = wid * 16 + (lane >> 3);      // j=0 row within half
    // A source element offsets (add k-offset per kt):
    const int a00 = (r0      ) * K_TOT + sd * 8;
    const int a01 = (r0 +   8) * K_TOT + sd * 8;
    const int a10 = (r0 + 128) * K_TOT + sd * 8;
    const int a11 = (r0 + 136) * K_TOT + sd * 8;
    // LDS dest offsets (ushorts; same pattern for As and Bs):
    const int d00 = (2 * wid + 0) * 512 + lane * 8;
    const int d01 = (2 * wid + 1) * 512 + lane * 8;
    const int d10 = 8192 + d00;
    const int d11 = 8192 + d01;
    // B pixel-base offsets:
    int p00, p01, p10, p11;
    {
        int pr, prow, pcol;
        pr = r0;         prow = pr >> 6; pcol = pr & 63; p00 = (prow * PAD + pcol) * 64 + sd * 8;
        pr = r0 + 8;     prow = pr >> 6; pcol = pr & 63; p01 = (prow * PAD + pcol) * 64 + sd * 8;
        pr = r0 + 128;   prow = pr >> 6; pcol = pr & 63; p10 = (prow * PAD + pcol) * 64 + sd * 8;
        pr = r0 + 136;   prow = pr >> 6; pcol = pr & 63; p11 = (prow * PAD + pcol) * 64 + sd * 8;
    }

#define STAGE_A(KTN, QN)                                                       \
    {                                                                          \
        int p_ = (KTN) >> 2, c4_ = (KTN) & 3;                                  \
        int ako = p_ * 256 + c4_ * 64;                                         \
        ushort_t* db = AsB + (QN) * 16384;                                     \
        gl_lds16(rwb + a00 + ako, db + d00);                                   \
        gl_lds16(rwb + a01 + ako, db + d01);                                   \
        gl_lds16(rwb + a10 + ako, db + d10);                                   \
        gl_lds16(rwb + a11 + ako, db + d11);                                   \
    }

#define STAGE_B(KTN, QN)                                                       \
    {                                                                          \
        int p_ = (KTN) >> 2, c4_ = (KTN) & 3;                                  \
        int ph_ = p_ / 3, pw_ = p_ - 3 * ph_;                                  \
        const ushort_t* sb = xtb + (size_t)(c4_ * PLANE + (y0 + ph_) * PAD + pw_) * 64; \
        ushort_t* db = BsB + (QN) * 16384;                                     \
        gl_lds16(sb + p00, db + d00);                                          \
        gl_lds16(sb + p01, db + d01);                                          \
        gl_lds16(sb + p10, db + d10);                                          \
        gl_lds16(sb + p11, db + d11);                                          \
    }

#define READ_AF(Q, MH2, KH)                                                    \
    _Pragma("unroll")                                                          \
    for (int mi = 0; mi < 4; ++mi) {                                           \
        int row = wm * 128 + (MH2) * 64 + mi * 16 + rA;                        \
        af[mi] = *(const short8*)(AsB + (Q) * 16384 + row * 64                 \
                                  + ((((KH) << 2) | kseg) ^ (rA & 7)) * 8);    \
    }

#define READ_BF(Q, KH)                                                         \
    _Pragma("unroll")                                                          \
    for (int ni = 0; ni < 4; ++ni) {                                           \
        int row = wn * 64 + ni * 16 + rA;                                      \
        bf[ni] = *(const short8*)(BsB + (Q) * 16384 + row * 64                 \
                                  + ((((KH) << 2) | kseg) ^ (rA & 7)) * 8);    \
    }

#define DO_MFMA(MH2)                                                           \
    __builtin_amdgcn_s_setprio(1);                                             \
    _Pragma("unroll")                                                          \
    for (int mi = 0; mi < 4; ++mi)                                             \
        _Pragma("unroll")                                                      \
        for (int ni = 0; ni < 4; ++ni)                                         \
            acc[(MH2) * 4 + mi][ni] = __builtin_amdgcn_mfma_f32_16x16x32_bf16( \
                af[mi], bf[ni], acc[(MH2) * 4 + mi][ni], 0, 0, 0);             \
    __builtin_amdgcn_s_setprio(0);

    // ---- prologue: stage kt=0 into buf 0 ----
    STAGE_A(0, 0);
    STAGE_B(0, 0);
    VMCNT0();
    BARRIER();

    short8 af[4], bf[4];
    for (int kt = 0; kt < NKT; ++kt) {
        int q = kt & 1, qn = q ^ 1;
        bool more = (kt + 1 < NKT);
        // phase 1: kh=0, m-half 0; stage A of kt+1
        READ_AF(q, 0, 0);
        READ_BF(q, 0);
        if (more) STAGE_A(kt + 1, qn);
        BARRIER();
        DO_MFMA(0);
        BARRIER();
        // phase 2: kh=0, m-half 1 (bf reused); stage B of kt+1
        READ_AF(q, 1, 0);
        if (more) STAGE_B(kt + 1, qn);
        BARRIER();
        DO_MFMA(1);
        BARRIER();
        // phase 3: kh=1, m-half 0
        READ_AF(q, 0, 1);
        READ_BF(q, 1);
        BARRIER();
        DO_MFMA(0);
        BARRIER();
        // phase 4: kh=1, m-half 1; drain stages before buffer swap
        READ_AF(q, 1, 1);
        BARRIER();
        DO_MFMA(1);
        VMCNT0();
        BARRIER();
    }
#undef STAGE_A
#undef STAGE_B
#undef READ_AF
#undef READ_BF
#undef DO_MFMA

    // ---- epilogue: D[row=(lane>>4)*4+rr][col=lane&15] ----
    int row0 = (lane >> 4) * 4;
    int col  = lane & 15;
    float* outb = out + (size_t)b * COUT * HW + tile * 256;
#pragma unroll
    for (int am = 0; am < 8; ++am)
#pragma unroll
        for (int an = 0; an < 4; ++an)
#pragma unroll
            for (int rr = 0; rr < 4; ++rr) {
                int m = wm * 128 + am * 16 + row0 + rr;
                int n = wn * 64 + an * 16 + col;
                outb[(size_t)m * HW + n] = acc[am][an][rr];
            }
}

// ---------------------------------------------------------------------------
extern "C" void kernel_launch(void* const* d_in, const int* in_sizes, int n_in,
                              void* d_out, int out_size, void* d_ws, size_t ws_size,
                              hipStream_t stream) {
    const float* x      = (const float*)d_in[0];
    const float* alphas = (const float*)d_in[1];
    const float* angles = (const float*)d_in[2];
    const float* weight = (const float*)d_in[3];
    float* out = (float*)d_out;

    // ws: rw 18.87 MB | xt 35.68 MB | rm 20.7 KB
    ushort_t* rw = (ushort_t*)d_ws;
    ushort_t* xt = (ushort_t*)((char*)d_ws + (size_t)B_ * COUT * K_TOT * 2);
    float*    rm = (float*)((char*)d_ws + (size_t)B_ * COUT * K_TOT * 2
                                        + (size_t)64 * PLANE * 64 * 2);

    rot_mats_kernel<<<1, 64, 0, stream>>>(alphas, angles, rm);
    build_rw_kernel<<<dim3(COUT * CIN / 256, B_), 256, 0, stream>>>(weight, rm, rw);
    halo_zero_kernel<<<64, 256, 0, stream>>>(xt);
    nhwc_kernel<<<dim3(64, 8, B_), 256, 0, stream>>>(x, xt);
    conv_kernel<<<256, 512, 0, stream>>>(xt, rw, out);
}